// Round 14
// baseline (1362.640 us; speedup 1.0000x reference)
//
#include <hip/hip_runtime.h>

// BiLSTM-CRF on MI355X. Round 14: K1 ce_s LDS XOR-swizzle (stride 64 words,
// word ^= (row&15)<<2) kills the 8-way bank conflict on conv cv reads.
// Everything else identical to round 13 (1074 us; k3=500).

#define DEV __device__ __forceinline__
typedef unsigned short u16;
typedef unsigned int   u32;
typedef unsigned char  u8;
typedef signed char    s8;
using short8  = __attribute__((ext_vector_type(8))) short;
using f32x4   = __attribute__((ext_vector_type(4))) float;
using int4v   = __attribute__((ext_vector_type(4))) int;

DEV float bf2f(u16 u){ union{u32 i; float f;} v; v.i = ((u32)u)<<16; return v.f; }
DEV u16 f2bf(float f){ u32 x = __float_as_uint(f); return (u16)((x + 0x7fffu + ((x>>16)&1u)) >> 16); }
DEV float sigf(float x){ return __builtin_amdgcn_rcpf(1.f + __expf(-x)); }
DEV float tanh_f(float x){ return 1.f - 2.f*__builtin_amdgcn_rcpf(__expf(2.f*x) + 1.f); }
DEV float rdlane_f(float v, int l){
  return __uint_as_float(__builtin_amdgcn_readlane(__float_as_uint(v), l));
}

typedef __attribute__((address_space(1))) const u32 GU;
typedef __attribute__((address_space(3))) u32 LU;
DEV void gld_lds16(const void* g, void* l){
  __builtin_amdgcn_global_load_lds((GU*)g, (LU*)l, 16, 0, 0);
}
DEV void bar_l(){
  __builtin_amdgcn_sched_barrier(0);
  asm volatile("s_waitcnt lgkmcnt(0)" ::: "memory");
  __builtin_amdgcn_s_barrier();
  __builtin_amdgcn_sched_barrier(0);
}

// ---------------- ws layout (aliased; total ~170MB) ----------------
static const size_t OFF_GI   = 0;
static const size_t OFF_P    = 0;
static const size_t OFF_DL   = OFF_P  + (size_t)32768*16*4;
static const size_t OFF_PSI  = OFF_DL + (size_t)32768*16*4;
static const size_t OFF_B    = (size_t)134217728;
static const size_t OFF_WIH  = OFF_B    + (size_t)33554432;
static const size_t OFF_WQ   = OFF_WIH  + (size_t)1703936;   // 512KB i8 frags
static const size_t OFF_SC   = OFF_WQ   + (size_t)524288;    // 8KB scales
static const size_t OFF_BIAS = OFF_SC   + 8192;
static const size_t OFF_WFC  = OFF_BIAS + 8192;
static const size_t REQUIRED = OFF_WFC  + 256;

// ---------------- K0all: quantize W_hh (0..511) | bias/wfc (512) | pack W_ih (513..2560) ----------------
__global__ __launch_bounds__(256) void k0_all(
    const float* __restrict__ whhf, const float* __restrict__ whhb,
    s8* __restrict__ wq, float* __restrict__ sc2,
    const float* bihf, const float* bhhf, const float* bihb, const float* bhhb,
    const float* fcw, const float* wdp, float* bias, float* wfc,
    const float* __restrict__ wihf, const float* __restrict__ wihb, u16* __restrict__ wih)
{
  __shared__ float red[256];
  const int tid = threadIdx.x;
  const int bx = blockIdx.x;
  if (bx > 512){
    const int n = bx - 513;
    const float* src = (n < 1024) ? (wihf + (size_t)n*400) : (wihb + (size_t)(n-1024)*400);
    u32* dst = (u32*)(wih + (size_t)n*416);
    if (tid < 208){
      int j = tid*2;
      u32 v = 0u;
      if (j < 400){
        float2 f = *(const float2*)(src + j);
        v = (u32)f2bf(f.x) | ((u32)f2bf(f.y) << 16);
      }
      dst[tid] = v;
    }
    return;
  }
  if (bx == 512){
    for (int n = tid; n < 2048; n += 256){
      bias[n] = (n < 1024) ? (bihf[n] + bhhf[n]) : (bihb[n-1024] + bhhb[n-1024]);
    }
    const int cur = tid & 15, part = tid >> 4;
    float s = 0.f;
    for (int k = part*32; k < part*32 + 32; k++) s += fcw[cur*512 + k] * wdp[k];
    red[tid] = s;
    __syncthreads();
    if (tid < 16){
      float t = 0.f;
      #pragma unroll
      for (int p = 0; p < 16; p++) t += red[p*16 + tid];
      wfc[tid] = t;
    }
    return;
  }
  const int row = bx*4 + (tid >> 6);
  const int lane = tid & 63;
  const float* src = (row < 1024) ? (whhf + (size_t)row*256)
                                  : (whhb + (size_t)(row-1024)*256);
  f32x4 v = *(const f32x4*)(src + lane*4);
  float m = fmaxf(fmaxf(fabsf(v[0]), fabsf(v[1])), fmaxf(fabsf(v[2]), fabsf(v[3])));
  #pragma unroll
  for (int d = 1; d < 64; d <<= 1) m = fmaxf(m, __shfl_xor(m, d, 64));
  float inv = 127.f / (m + 1e-30f);
  u32 pack = 0;
  #pragma unroll
  for (int e = 0; e < 4; e++){
    int q = (int)rintf(v[e]*inv);
    q = q > 127 ? 127 : (q < -127 ? -127 : q);
    pack |= ((u32)(u8)(s8)q) << (8*e);
  }
  const int dir = row >> 10, n = row & 1023;
  const int g = n >> 8, j = n & 255, w2 = j >> 4, lr2 = j & 15;
  const int kk = lane >> 4, lq2 = (lane >> 2) & 3, e4 = lane & 3;
  u32* wq32 = (u32*)wq;
  wq32[dir*65536 + (((g*16 + w2)*4 + kk)*64 + lq2*16 + lr2)*4 + e4] = pack;
  if (lane == 0) sc2[row] = m * (1.f/16129.f);
}

// ---------------- K1: features; ce_s XOR-swizzled (stride 64w, ^ (row&15)<<2) ----------------
#define CES(r, c) (((r) << 6) + ((c) ^ ((((r) & 15)) << 2)))
__global__ __launch_bounds__(256) void k1_feat(
    const int* __restrict__ X, const int* __restrict__ tg, const int* __restrict__ ch,
    const float* __restrict__ etab, const float* __restrict__ ttab, const float* __restrict__ ctab,
    const float* __restrict__ cw, const float* __restrict__ cb, u16* __restrict__ feat)
{
  const int b = blockIdx.y, tid = threadIdx.x;
  __shared__ float ce_s[66*64];
  __shared__ float w_s[150*52];
  for (int i = tid; i < 7500; i += 256){
    int cc = i/150, r2 = i - cc*150;
    int ce = r2/3, dc = r2 - ce*3;
    w_s[(cc*3 + dc)*52 + ce] = cw[i];
  }
  const int li = tid & 15, jg = tid >> 4;

  for (int it = 0; it < 8; it++){
    const int sb = blockIdx.x*8 + it;
    __syncthreads();
    for (int i = tid; i < 600; i += 256){
      int wl = i/150, j = i - wl*150;
      int s = sb*4 + wl;
      int idx = X[b*512 + s];
      float2 f = *(const float2*)(etab + (size_t)idx*300 + j*2);
      *(u32*)(feat + (size_t)(s*64 + b)*416 + j*2) = (u32)f2bf(f.x) | ((u32)f2bf(f.y) << 16);
    }
    for (int i = tid; i < 100; i += 256){
      int wl = i/25, j = i - wl*25;
      int s = sb*4 + wl;
      int idx = tg[b*512 + s];
      float2 f = *(const float2*)(ttab + (size_t)idx*50 + j*2);
      *(u32*)(feat + (size_t)(s*64 + b)*416 + 300 + j*2) = (u32)f2bf(f.x) | ((u32)f2bf(f.y) << 16);
    }
    if (tid < 32){
      int wl = tid>>3, j = tid&7;
      int s = sb*4 + wl;
      *(u32*)(feat + (size_t)(s*64 + b)*416 + 400 + j*2) = 0u;
    }
    for (int i = tid; i < 3300; i += 256){
      int qq = i/50, ce = i - qq*50;
      int p = sb*64 - 1 + qq;
      float v = 0.f;
      if (p >= 0 && p < 8192){
        int ci = ch[b*8192 + p];
        v = ctab[ci*50 + ce];
      }
      ce_s[CES(qq, ce)] = v;
    }
    __syncthreads();
    float acc[4][3];
    #pragma unroll
    for (int k=0;k<4;k++){ acc[k][0]=0.f; acc[k][1]=0.f; acc[k][2]=0.f; }
    #pragma unroll
    for (int dc = 0; dc < 3; dc++){
      for (int ceb = 0; ceb < 48; ceb += 4){
        f32x4 w0 = *(const f32x4*)&w_s[((3*jg+0)*3 + dc)*52 + ceb];
        f32x4 w1 = *(const f32x4*)&w_s[((3*jg+1)*3 + dc)*52 + ceb];
        f32x4 w2 = *(const f32x4*)&w_s[((3*jg+2)*3 + dc)*52 + ceb];
        #pragma unroll
        for (int k = 0; k < 4; k++){
          f32x4 cv = *(const f32x4*)&ce_s[CES(16*k + li + dc, ceb)];
          #pragma unroll
          for (int e = 0; e < 4; e++){
            acc[k][0] += cv[e]*w0[e];
            acc[k][1] += cv[e]*w1[e];
            acc[k][2] += cv[e]*w2[e];
          }
        }
      }
      float w0a = w_s[((3*jg+0)*3+dc)*52 + 48], w0b = w_s[((3*jg+0)*3+dc)*52 + 49];
      float w1a = w_s[((3*jg+1)*3+dc)*52 + 48], w1b = w_s[((3*jg+1)*3+dc)*52 + 49];
      float w2a = w_s[((3*jg+2)*3+dc)*52 + 48], w2b = w_s[((3*jg+2)*3+dc)*52 + 49];
      #pragma unroll
      for (int k = 0; k < 4; k++){
        const int rw = 16*k + li + dc;
        float ca  = ce_s[CES(rw, 48)];
        float cb2 = ce_s[CES(rw, 49)];
        acc[k][0] += ca*w0a + cb2*w0b;
        acc[k][1] += ca*w1a + cb2*w1b;
        acc[k][2] += ca*w2a + cb2*w2b;
      }
    }
    #pragma unroll
    for (int m = 1; m < 16; m <<= 1)
      #pragma unroll
      for (int k=0;k<4;k++)
        #pragma unroll
        for (int c=0;c<3;c++)
          acc[k][c] = fmaxf(acc[k][c], __shfl_xor(acc[k][c], m, 64));
    if (li == 0){
      #pragma unroll
      for (int k=0;k<4;k++)
        #pragma unroll
        for (int c=0;c<3;c++){
          int cc = 3*jg + c;
          int s = sb*4 + k;
          feat[(size_t)(s*64 + b)*416 + 350 + cc] = f2bf(acc[k][c] + cb[cc]);
        }
    }
    if (tid < 128){
      int pl = tid & 63, cc = 48 + (tid >> 6);
      float a2 = 0.f;
      #pragma unroll
      for (int dc = 0; dc < 3; dc++){
        for (int ceb = 0; ceb < 48; ceb += 4){
          f32x4 wv = *(const f32x4*)&w_s[(cc*3 + dc)*52 + ceb];
          f32x4 cv = *(const f32x4*)&ce_s[CES(pl + dc, ceb)];
          a2 += cv[0]*wv[0] + cv[1]*wv[1] + cv[2]*wv[2] + cv[3]*wv[3];
        }
        a2 += ce_s[CES(pl+dc, 48)]*w_s[(cc*3+dc)*52 + 48]
            + ce_s[CES(pl+dc, 49)]*w_s[(cc*3+dc)*52 + 49];
      }
      #pragma unroll
      for (int m = 1; m < 16; m <<= 1) a2 = fmaxf(a2, __shfl_xor(a2, m, 64));
      if ((tid & 15) == 0){
        int s = sb*4 + ((tid & 63) >> 4);
        feat[(size_t)(s*64 + b)*416 + 350 + cc] = f2bf(a2 + cb[cc]);
      }
    }
  }
}
#undef CES

// ---------------- K2: gi = bf16(feat @ wih^T + bias), double-buffered LDS ----------------
__global__ __launch_bounds__(256) void k2_gemm(
    const u16* __restrict__ featp, const u16* __restrict__ wihp,
    const float* __restrict__ bias, u16* __restrict__ gi)
{
  const int m0 = blockIdx.y*128, n0 = blockIdx.x*128;
  const int tid = threadIdx.x, wv = tid>>6, lane = tid&63;
  const int lr = lane & 15, lq = lane >> 4;
  const int wm = (wv>>1)*64, wn = (wv&1)*64;
  __shared__ u16 As[2][4096], Bs[2][4096];
  f32x4 acc[4][4];
  #pragma unroll
  for (int a=0;a<4;a++)
    #pragma unroll
    for (int c=0;c<4;c++) acc[a][c] = (f32x4){0.f,0.f,0.f,0.f};

  #define K2_STAGE(BUF, K0) { \
    _Pragma("unroll") \
    for (int i = 0; i < 2; i++){ \
      int c = i*4 + wv; \
      gld_lds16(featp + (size_t)(m0 + c*16 + (lane>>2))*416 + (K0) + (lane&3)*8, &As[BUF][c*512]); \
      gld_lds16(wihp  + (size_t)(n0 + c*16 + (lane>>2))*416 + (K0) + (lane&3)*8, &Bs[BUF][c*512]); \
    } }

  K2_STAGE(0, 0);
  __syncthreads();
  int buf = 0;
  for (int ki = 0; ki < 13; ki++){
    if (ki < 12) K2_STAGE(buf^1, (ki+1)*32);
    short8 af[4], bfr[4];
    #pragma unroll
    for (int mt=0; mt<4; mt++) af[mt]  = *(const short8*)(&As[buf][0] + (wm + mt*16 + lr)*32 + lq*8);
    #pragma unroll
    for (int nt=0; nt<4; nt++) bfr[nt] = *(const short8*)(&Bs[buf][0] + (wn + nt*16 + lr)*32 + lq*8);
    #pragma unroll
    for (int mt=0; mt<4; mt++)
      #pragma unroll
      for (int nt=0; nt<4; nt++)
        acc[mt][nt] = __builtin_amdgcn_mfma_f32_16x16x32_bf16(af[mt], bfr[nt], acc[mt][nt], 0,0,0);
    __syncthreads();
    buf ^= 1;
  }
  #undef K2_STAGE
  #pragma unroll
  for (int nt=0; nt<4; nt++){
    float bv = bias[n0 + wn + nt*16 + lr];
    #pragma unroll
    for (int mt=0; mt<4; mt++)
      #pragma unroll
      for (int r=0; r<4; r++)
        gi[(size_t)(m0 + wm + mt*16 + lq*4 + r)*2048 + n0 + wn + nt*16 + lr]
            = f2bf(acc[mt][nt][r] + bv);
  }
}

// ---------------- K3: recurrent BiLSTM, 64 blocks x 512 thr, all-VGPR weights ----------------
__global__ __launch_bounds__(512, 2) void k3_lstm(
    const s8* __restrict__ wq, const float* __restrict__ sc2,
    const u16* __restrict__ gi, u16* __restrict__ hcat)
{
  const int dir = blockIdx.x >> 5;
  const int bb  = (blockIdx.x & 31) * 2;
  const int tid = threadIdx.x;
  const int w = tid >> 6, lane = tid & 63;
  const int lr = lane & 15, lq = lane >> 4;
  const int cb = tid >> 8, cj = tid & 255;

  __shared__ s8 Hs[2][4096];
  __shared__ float xbuf[2048];

  const s8* wqd = wq + dir*262144;
  int4v bq[2][4][4];
  #pragma unroll
  for (int sl = 0; sl < 2; sl++)
    #pragma unroll
    for (int g = 0; g < 4; g++)
      #pragma unroll
      for (int kk = 0; kk < 4; kk++)
        bq[sl][g][kk] = *(const int4v*)(wqd + (((((g*16 + 2*w + sl)*4 + kk)*64) + lane) << 4));

  float scl[4];
  #pragma unroll
  for (int g = 0; g < 4; g++) scl[g] = sc2[dir*1024 + g*256 + cj];

  *(uint2*)&Hs[0][tid*8] = (uint2){0u,0u};
  *(uint2*)&Hs[1][tid*8] = (uint2){0u,0u};

  float cst = 0.f;
  const ptrdiff_t dstep = dir ? -(ptrdiff_t)131072 : (ptrdiff_t)131072;
  const u16* g0 = gi + (size_t)((dir ? 511 : 0)*64 + bb + cb)*2048 + dir*1024 + cj;
  u32 gcur[4], gn1[4], gn2[4];
  #pragma unroll
  for (int g = 0; g < 4; g++) gcur[g] = g0[g*256];
  const u16* g1 = g0 + dstep;
  #pragma unroll
  for (int g = 0; g < 4; g++) gn1[g] = g1[g*256];
  const u16* gpref = g1;
  __syncthreads();

  #pragma unroll 1
  for (int t = 0; t < 512; t++){
    const int s = dir ? (511 - t) : t;
    if (t + 2 < 512) gpref += dstep;
    #pragma unroll
    for (int g = 0; g < 4; g++) gn2[g] = gpref[g*256];
    const s8* hb = Hs[t & 1];
    int4v aq[4];
    #pragma unroll
    for (int kk = 0; kk < 4; kk++)
      aq[kk] = *(const int4v*)(hb + lr*256 + ((kk*64 + lq*16) ^ (lr << 4)));
    int4v acc[2][4];
    #pragma unroll
    for (int sl = 0; sl < 2; sl++)
      #pragma unroll
      for (int g = 0; g < 4; g++) acc[sl][g] = (int4v){0,0,0,0};
    __builtin_amdgcn_s_setprio(1);
    #pragma unroll
    for (int kk = 0; kk < 4; kk++)
      #pragma unroll
      for (int sl = 0; sl < 2; sl++)
        #pragma unroll
        for (int g = 0; g < 4; g++)
          acc[sl][g] = __builtin_amdgcn_mfma_i32_16x16x64_i8(aq[kk], bq[sl][g][kk], acc[sl][g], 0,0,0);
    __builtin_amdgcn_s_setprio(0);
    if (lq == 0){
      #pragma unroll
      for (int sl = 0; sl < 2; sl++){
        const int j = (2*w + sl)*16 + lr;
        #pragma unroll
        for (int r = 0; r < 2; r++){
          f32x4 v = (f32x4){(float)acc[sl][0][r], (float)acc[sl][1][r],
                            (float)acc[sl][2][r], (float)acc[sl][3][r]};
          *(f32x4*)&xbuf[(r*256 + j)*4] = v;
        }
      }
    }
    bar_l();
    f32x4 p = *(const f32x4*)&xbuf[tid*4];
    float g4[4];
    #pragma unroll
    for (int g = 0; g < 4; g++) g4[g] = bf2f((u16)gcur[g]) + p[g]*scl[g];
    float iv = sigf(g4[0]), fv = sigf(g4[1]);
    float gg = tanh_f(g4[2]), ov = sigf(g4[3]);
    float c = fv*cst + iv*gg;
    cst = c;
    float h = ov * tanh_f(c);
    hcat[(size_t)(s*64 + bb + cb)*512 + dir*256 + cj] = f2bf(h);
    Hs[(t + 1) & 1][cb*256 + (cj ^ (cb << 4))] = (s8)(int)rintf(h * 127.f);
    #pragma unroll
    for (int g = 0; g < 4; g++){ gcur[g] = gn1[g]; gn1[g] = gn2[g]; }
    bar_l();
  }
}

// ---------------- K4: P = Hcat @ fc_w^T + fc_b + lm*wfc  [32768 x 16] fp32 ----------------
__global__ __launch_bounds__(256) void k4_fc(
    const u16* __restrict__ hcat, const float* __restrict__ fcw, const float* __restrict__ fcb,
    const float* __restrict__ lmp, const float* __restrict__ wfc, float* __restrict__ Pout)
{
  const int wv = threadIdx.x >> 6, lane = threadIdx.x & 63;
  const int lr = lane & 15, lq = lane >> 4;
  const int mt = blockIdx.x*4 + wv;
  short8 bfr[16];
  #pragma unroll
  for (int kk = 0; kk < 16; kk++){
    const float* wr = fcw + (size_t)lr*512 + kk*32 + lq*8;
    f32x4 w0 = *(const f32x4*)wr;
    f32x4 w1 = *(const f32x4*)(wr + 4);
    short8 sv;
    #pragma unroll
    for (int e = 0; e < 4; e++){ sv[e] = (short)f2bf(w0[e]); sv[4+e] = (short)f2bf(w1[e]); }
    bfr[kk] = sv;
  }
  f32x4 acc = (f32x4){0.f,0.f,0.f,0.f};
  #pragma unroll
  for (int kk = 0; kk < 16; kk++){
    short8 af = *(const short8*)(hcat + (size_t)(mt*16 + lr)*512 + kk*32 + lq*8);
    acc = __builtin_amdgcn_mfma_f32_16x16x32_bf16(af, bfr[kk], acc, 0,0,0);
  }
  const int cur = lr;
  float fb = fcb[cur];
  float wf = wfc[cur];
  #pragma unroll
  for (int r = 0; r < 4; r++){
    int m = mt*16 + lq*4 + r;
    int b = m & 63, s = m >> 6;
    float lmv = lmp[b*512 + s];
    Pout[(size_t)m*16 + cur] = acc[r] + fb + lmv*wf;
  }
}

// ---------------- K5: Viterbi — shuffle-free (replicated delta + readlane) ----------------
__global__ __launch_bounds__(64) void k5_vit(
    const float* __restrict__ Pg, const float* __restrict__ Am,
    float* __restrict__ dout, float* __restrict__ dl, u8* __restrict__ psi)
{
  const int b = blockIdx.x, lane = threadIdx.x;
  const int cur = lane & 15;
  float Ar[16];
  #pragma unroll
  for (int p = 0; p < 16; p++) Ar[p] = Am[p*16 + cur];
  float dreg[16];
  {
    float v0 = Pg[(size_t)b*16 + cur];
    if (lane < 16) dl[(size_t)b*16 + cur] = v0;
    #pragma unroll
    for (int c = 0; c < 16; c++) dreg[c] = rdlane_f(v0, c);
  }

#define FSTEP(X, S) { \
    float v_[16]; \
    _Pragma("unroll") \
    for (int p = 0; p < 16; p++) v_[p] = dreg[p] + Ar[p]; \
    float m1[8]; int i1[8]; \
    _Pragma("unroll") \
    for (int k = 0; k < 8; k++){ bool c_ = v_[2*k] >= v_[2*k+1]; \
      m1[k] = c_ ? v_[2*k] : v_[2*k+1]; i1[k] = c_ ? 2*k : 2*k+1; } \
    float m2[4]; int i2[4]; \
    _Pragma("unroll") \
    for (int k = 0; k < 4; k++){ bool c_ = m1[2*k] >= m1[2*k+1]; \
      m2[k] = c_ ? m1[2*k] : m1[2*k+1]; i2[k] = c_ ? i1[2*k] : i1[2*k+1]; } \
    float m3[2]; int i3[2]; \
    _Pragma("unroll") \
    for (int k = 0; k < 2; k++){ bool c_ = m2[2*k] >= m2[2*k+1]; \
      m3[k] = c_ ? m2[2*k] : m2[2*k+1]; i3[k] = c_ ? i2[2*k] : i2[2*k+1]; } \
    bool cf_ = m3[0] >= m3[1]; \
    float best = (cf_ ? m3[0] : m3[1]) + (X); \
    int bi = cf_ ? i3[0] : i3[1]; \
    if (lane < 16){ \
      dl[(size_t)((S)*64 + b)*16 + cur] = best; \
      psi[(size_t)((S)*64 + b)*16 + cur] = (u8)bi; \
    } \
    _Pragma("unroll") \
    for (int c = 0; c < 16; c++) dreg[c] = rdlane_f(best, c); \
  }

  float x0 = Pg[(size_t)(1*64 + b)*16 + cur];
  float x1 = Pg[(size_t)(2*64 + b)*16 + cur];
  float x2 = Pg[(size_t)(3*64 + b)*16 + cur];
  float x3 = Pg[(size_t)(4*64 + b)*16 + cur];
  for (int s = 1; s < 512; s += 4){
    FSTEP(x0, s);
    if (s + 4 < 512) x0 = Pg[(size_t)((s+4)*64 + b)*16 + cur];
    if (s + 1 < 512) FSTEP(x1, s+1);
    if (s + 5 < 512) x1 = Pg[(size_t)((s+5)*64 + b)*16 + cur];
    if (s + 2 < 512) FSTEP(x2, s+2);
    if (s + 6 < 512) x2 = Pg[(size_t)((s+6)*64 + b)*16 + cur];
    if (s + 3 < 512) FSTEP(x3, s+3);
    if (s + 7 < 512) x3 = Pg[(size_t)((s+7)*64 + b)*16 + cur];
  }
#undef FSTEP

  float bv = dreg[0]; int bix = 0;
  #pragma unroll
  for (int c = 1; c < 16; c++){ if (dreg[c] > bv){ bv = dreg[c]; bix = c; } }
  int tag = bix;
  float score = bv;
  if (lane == 0) dout[b*512 + 511] = (float)tag;

#define BSTEP(PV, DV, T) { \
    int prev = __builtin_amdgcn_readlane((PV), tag); \
    score += rdlane_f((DV), prev); \
    if (lane == 0) dout[b*512 + (T)] = (float)prev; \
    tag = prev; }

  int   p0 = 0, p1 = 0, p2 = 0, p3 = 0;
  float d0 = 0.f, d1 = 0.f, d2 = 0.f, d3 = 0.f;
  if (lane < 16){
    p0 = psi[(size_t)(511*64 + b)*16 + lane]; d0 = dl[(size_t)(510*64 + b)*16 + lane];
    p1 = psi[(size_t)(510*64 + b)*16 + lane]; d1 = dl[(size_t)(509*64 + b)*16 + lane];
    p2 = psi[(size_t)(509*64 + b)*16 + lane]; d2 = dl[(size_t)(508*64 + b)*16 + lane];
    p3 = psi[(size_t)(508*64 + b)*16 + lane]; d3 = dl[(size_t)(507*64 + b)*16 + lane];
  }
  for (int t = 510; t >= 0; t -= 4){
    BSTEP(p0, d0, t);
    if (t - 4 >= 0 && lane < 16){
      p0 = psi[(size_t)((t-3)*64 + b)*16 + lane]; d0 = dl[(size_t)((t-4)*64 + b)*16 + lane];
    }
    if (t - 1 >= 0) BSTEP(p1, d1, t-1);
    if (t - 5 >= 0 && lane < 16){
      p1 = psi[(size_t)((t-4)*64 + b)*16 + lane]; d1 = dl[(size_t)((t-5)*64 + b)*16 + lane];
    }
    if (t - 2 >= 0) BSTEP(p2, d2, t-2);
    if (t - 6 >= 0 && lane < 16){
      p2 = psi[(size_t)((t-5)*64 + b)*16 + lane]; d2 = dl[(size_t)((t-6)*64 + b)*16 + lane];
    }
    if (t - 3 >= 0) BSTEP(p3, d3, t-3);
    if (t - 7 >= 0 && lane < 16){
      p3 = psi[(size_t)((t-6)*64 + b)*16 + lane]; d3 = dl[(size_t)((t-7)*64 + b)*16 + lane];
    }
  }
#undef BSTEP
  if (lane == 0) dout[32768 + b] = score;
}

// ---------------- launcher ----------------
extern "C" void kernel_launch(void* const* d_in, const int* in_sizes, int n_in,
                              void* d_out, int out_size, void* d_ws, size_t ws_size,
                              hipStream_t stream)
{
  (void)in_sizes; (void)n_in; (void)out_size;
  if (ws_size < REQUIRED) return;

  const int*   X    = (const int*)d_in[0];
  const float* lm   = (const float*)d_in[1];
  const int*   tg   = (const int*)d_in[2];
  const int*   ch   = (const int*)d_in[3];
  const float* etab = (const float*)d_in[4];
  const float* ttab = (const float*)d_in[5];
  const float* ctab = (const float*)d_in[6];
  const float* cw   = (const float*)d_in[7];
  const float* cb   = (const float*)d_in[8];
  const float* wihf = (const float*)d_in[9];
  const float* whhf = (const float*)d_in[10];
  const float* bihf = (const float*)d_in[11];
  const float* bhhf = (const float*)d_in[12];
  const float* wihb = (const float*)d_in[13];
  const float* whhb = (const float*)d_in[14];
  const float* bihb = (const float*)d_in[15];
  const float* bhhb = (const float*)d_in[16];
  const float* fcw  = (const float*)d_in[17];
  const float* fcb  = (const float*)d_in[18];
  const float* Am   = (const float*)d_in[19];
  const float* wdp  = (const float*)d_in[20];

  char* ws = (char*)d_ws;
  u16*   gi   = (u16*)(ws + OFF_GI);
  u16*   feat = (u16*)(ws + OFF_B);
  u16*   hcat = (u16*)(ws + OFF_B);
  u16*   wih  = (u16*)(ws + OFF_WIH);
  s8*    wq   = (s8*)(ws + OFF_WQ);
  float* sc2  = (float*)(ws + OFF_SC);
  float* Pg   = (float*)(ws + OFF_P);
  float* dlt  = (float*)(ws + OFF_DL);
  u8*    psi  = (u8*)(ws + OFF_PSI);
  float* bias = (float*)(ws + OFF_BIAS);
  float* wfc  = (float*)(ws + OFF_WFC);
  float* dout = (float*)d_out;

  k0_all<<<2561, 256, 0, stream>>>(whhf, whhb, wq, sc2,
                                   bihf, bhhf, bihb, bhhb, fcw, wdp, bias, wfc,
                                   wihf, wihb, wih);
  k1_feat<<<dim3(16, 64), 256, 0, stream>>>(X, tg, ch, etab, ttab, ctab, cw, cb, feat);
  k2_gemm<<<dim3(16, 256), 256, 0, stream>>>(feat, wih, bias, gi);
  k3_lstm<<<64, 512, 0, stream>>>(wq, sc2, gi, hcat);
  k4_fc<<<512, 256, 0, stream>>>(hcat, fcw, fcb, lm, wfc, Pg);
  k5_vit<<<64, 64, 0, stream>>>(Pg, Am, dout, dlt, psi);
}

// Round 15
// 1071.731 us; speedup vs baseline: 1.2714x; 1.2714x over previous
//
#include <hip/hip_runtime.h>

// BiLSTM-CRF on MI355X. Round 15: swizzle REVERTED (regressed 232->520).
// k0+k1 fused into one kernel with 3 block types running concurrently:
//   [0,1024)    conv blocks: char-gather reg-staged (T14), lgkm-only barriers
//   [1024,3072) copy blocks: embed/tag/pad rows of feat (no LDS, no barriers)
//   [3072,5633) k0 blocks: W_hh quantize | bias/wfc | W_ih pack
// K2 (dbuf), K3 (500us), K4, K5 frozen from round 13.

#define DEV __device__ __forceinline__
typedef unsigned short u16;
typedef unsigned int   u32;
typedef unsigned char  u8;
typedef signed char    s8;
using short8  = __attribute__((ext_vector_type(8))) short;
using f32x4   = __attribute__((ext_vector_type(4))) float;
using int4v   = __attribute__((ext_vector_type(4))) int;

DEV float bf2f(u16 u){ union{u32 i; float f;} v; v.i = ((u32)u)<<16; return v.f; }
DEV u16 f2bf(float f){ u32 x = __float_as_uint(f); return (u16)((x + 0x7fffu + ((x>>16)&1u)) >> 16); }
DEV u32 pk2(float a, float b){ return (u32)f2bf(a) | ((u32)f2bf(b) << 16); }
DEV float sigf(float x){ return __builtin_amdgcn_rcpf(1.f + __expf(-x)); }
DEV float tanh_f(float x){ return 1.f - 2.f*__builtin_amdgcn_rcpf(__expf(2.f*x) + 1.f); }
DEV float rdlane_f(float v, int l){
  return __uint_as_float(__builtin_amdgcn_readlane(__float_as_uint(v), l));
}

typedef __attribute__((address_space(1))) const u32 GU;
typedef __attribute__((address_space(3))) u32 LU;
DEV void gld_lds16(const void* g, void* l){
  __builtin_amdgcn_global_load_lds((GU*)g, (LU*)l, 16, 0, 0);
}
DEV void bar_l(){
  __builtin_amdgcn_sched_barrier(0);
  asm volatile("s_waitcnt lgkmcnt(0)" ::: "memory");
  __builtin_amdgcn_s_barrier();
  __builtin_amdgcn_sched_barrier(0);
}

// ---------------- ws layout (aliased; total ~170MB) ----------------
static const size_t OFF_GI   = 0;
static const size_t OFF_P    = 0;
static const size_t OFF_DL   = OFF_P  + (size_t)32768*16*4;
static const size_t OFF_PSI  = OFF_DL + (size_t)32768*16*4;
static const size_t OFF_B    = (size_t)134217728;
static const size_t OFF_WIH  = OFF_B    + (size_t)33554432;
static const size_t OFF_WQ   = OFF_WIH  + (size_t)1703936;   // 512KB i8 frags
static const size_t OFF_SC   = OFF_WQ   + (size_t)524288;    // 8KB scales
static const size_t OFF_BIAS = OFF_SC   + 8192;
static const size_t OFF_WFC  = OFF_BIAS + 8192;
static const size_t REQUIRED = OFF_WFC  + 256;

// ---------------- K01: fused conv / feat-copy / k0 ----------------
__global__ __launch_bounds__(256) void k01_fused(
    const int* __restrict__ X, const int* __restrict__ tg, const int* __restrict__ ch,
    const float* __restrict__ etab, const float* __restrict__ ttab, const float* __restrict__ ctab,
    const float* __restrict__ cw, const float* __restrict__ cb, u16* __restrict__ feat,
    const float* __restrict__ whhf, const float* __restrict__ whhb,
    s8* __restrict__ wq, float* __restrict__ sc2,
    const float* bihf, const float* bhhf, const float* bihb, const float* bhhb,
    const float* fcw, const float* wdp, float* bias, float* wfc,
    const float* __restrict__ wihf, const float* __restrict__ wihb, u16* __restrict__ wih)
{
  __shared__ float smem[3960 + 7800];   // ce_s[66*60] | w_s[150*52]
  const int tid = threadIdx.x;
  const int bid = blockIdx.x;

  if (bid < 1024){
    // ---------- conv blocks ----------
    float* ce_s = smem;
    float* w_s  = smem + 3960;
    const int b = bid >> 4, sbb = bid & 15;
    for (int i = tid; i < 7500; i += 256){
      int cc = i/150, r2 = i - cc*150;
      int ce = r2/3, dc = r2 - ce*3;
      w_s[(cc*3 + dc)*52 + ce] = cw[i];
    }
    const int li = tid & 15, jg = tid >> 4;
    float stg[13];

    #define GATHER(T) { \
      const int sbg = sbb*8 + (T); \
      _Pragma("unroll") \
      for (int j = 0; j < 13; j++){ \
        int i = tid + 256*j; \
        float v = 0.f; \
        if (i < 3300){ \
          int qq = i/50, ce = i - qq*50; \
          int p = sbg*64 - 1 + qq; \
          if (p >= 0 && p < 8192){ int ci = ch[b*8192 + p]; v = ctab[ci*50 + ce]; } \
        } \
        stg[j] = v; \
      } }

    GATHER(0);
    for (int t = 0; t < 8; t++){
      const int sb = sbb*8 + t;
      bar_l();                     // prev conv done reading ce_s (lgkm only)
      #pragma unroll
      for (int j = 0; j < 13; j++){
        int i = tid + 256*j;
        if (i < 3300){
          int qq = i/50, ce = i - qq*50;
          ce_s[qq*60 + ce] = stg[j];
        }
      }
      bar_l();                     // ce_s visible (lgkm only; gathers stay in flight)
      if (t < 7) GATHER(t+1);      // T14: issue next tile's gather before conv

      float acc[4][3];
      #pragma unroll
      for (int k=0;k<4;k++){ acc[k][0]=0.f; acc[k][1]=0.f; acc[k][2]=0.f; }
      #pragma unroll
      for (int dc = 0; dc < 3; dc++){
        for (int ceb = 0; ceb < 48; ceb += 4){
          f32x4 w0 = *(const f32x4*)&w_s[((3*jg+0)*3 + dc)*52 + ceb];
          f32x4 w1 = *(const f32x4*)&w_s[((3*jg+1)*3 + dc)*52 + ceb];
          f32x4 w2 = *(const f32x4*)&w_s[((3*jg+2)*3 + dc)*52 + ceb];
          #pragma unroll
          for (int k = 0; k < 4; k++){
            f32x4 cv = *(const f32x4*)&ce_s[(16*k + li + dc)*60 + ceb];
            #pragma unroll
            for (int e = 0; e < 4; e++){
              acc[k][0] += cv[e]*w0[e];
              acc[k][1] += cv[e]*w1[e];
              acc[k][2] += cv[e]*w2[e];
            }
          }
        }
        float w0a = w_s[((3*jg+0)*3+dc)*52 + 48], w0b = w_s[((3*jg+0)*3+dc)*52 + 49];
        float w1a = w_s[((3*jg+1)*3+dc)*52 + 48], w1b = w_s[((3*jg+1)*3+dc)*52 + 49];
        float w2a = w_s[((3*jg+2)*3+dc)*52 + 48], w2b = w_s[((3*jg+2)*3+dc)*52 + 49];
        #pragma unroll
        for (int k = 0; k < 4; k++){
          float ca  = ce_s[(16*k + li + dc)*60 + 48];
          float cb2 = ce_s[(16*k + li + dc)*60 + 49];
          acc[k][0] += ca*w0a + cb2*w0b;
          acc[k][1] += ca*w1a + cb2*w1b;
          acc[k][2] += ca*w2a + cb2*w2b;
        }
      }
      #pragma unroll
      for (int m = 1; m < 16; m <<= 1)
        #pragma unroll
        for (int k=0;k<4;k++)
          #pragma unroll
          for (int c=0;c<3;c++)
            acc[k][c] = fmaxf(acc[k][c], __shfl_xor(acc[k][c], m, 64));
      if (li == 0){
        #pragma unroll
        for (int k=0;k<4;k++)
          #pragma unroll
          for (int c=0;c<3;c++){
            int cc = 3*jg + c;
            int s = sb*4 + k;
            feat[(size_t)(s*64 + b)*416 + 350 + cc] = f2bf(acc[k][c] + cb[cc]);
          }
      }
      if (tid < 128){
        int pl = tid & 63, cc = 48 + (tid >> 6);
        float a2 = 0.f;
        #pragma unroll
        for (int dc = 0; dc < 3; dc++){
          for (int ceb = 0; ceb < 48; ceb += 4){
            f32x4 wv = *(const f32x4*)&w_s[(cc*3 + dc)*52 + ceb];
            f32x4 cv = *(const f32x4*)&ce_s[(pl + dc)*60 + ceb];
            a2 += cv[0]*wv[0] + cv[1]*wv[1] + cv[2]*wv[2] + cv[3]*wv[3];
          }
          a2 += ce_s[(pl+dc)*60 + 48]*w_s[(cc*3+dc)*52 + 48]
              + ce_s[(pl+dc)*60 + 49]*w_s[(cc*3+dc)*52 + 49];
        }
        #pragma unroll
        for (int m = 1; m < 16; m <<= 1) a2 = fmaxf(a2, __shfl_xor(a2, m, 64));
        if ((tid & 15) == 0){
          int s = sb*4 + ((tid & 63) >> 4);
          feat[(size_t)(s*64 + b)*416 + 350 + cc] = f2bf(a2 + cb[cc]);
        }
      }
    }
    #undef GATHER
    return;
  }

  if (bid < 3072){
    // ---------- copy blocks: embed/tag/pad rows of feat ----------
    const int cid = bid - 1024;           // 0..2047, 16 rows each
    const int w = tid >> 6, lane = tid & 63;
    #pragma unroll
    for (int r = 0; r < 4; r++){
      const int m = cid*16 + w*4 + r;     // row = s*64+b
      const int s = m >> 6, b = m & 63;
      const int xi = X[b*512 + s];
      const int ti = tg[b*512 + s];
      u32* dst = (u32*)feat + (size_t)m*208;
      #pragma unroll
      for (int pass = 0; pass < 3; pass++){
        int word = pass*64 + lane;
        if (word < 150){
          float2 f = *(const float2*)(etab + (size_t)xi*300 + word*2);
          dst[word] = pk2(f.x, f.y);
        } else if (word < 175){
          float2 f = *(const float2*)(ttab + (size_t)ti*50 + (word-150)*2);
          dst[word] = pk2(f.x, f.y);
        } else if (word < 183){
          dst[200 + word - 175] = 0u;
        }
      }
    }
    return;
  }

  // ---------- k0 blocks ----------
  const int bx = bid - 3072;              // 0..2560
  if (bx > 512){
    const int n = bx - 513;
    const float* src = (n < 1024) ? (wihf + (size_t)n*400) : (wihb + (size_t)(n-1024)*400);
    u32* dst = (u32*)(wih + (size_t)n*416);
    if (tid < 208){
      int j = tid*2;
      u32 v = 0u;
      if (j < 400){
        float2 f = *(const float2*)(src + j);
        v = pk2(f.x, f.y);
      }
      dst[tid] = v;
    }
    return;
  }
  if (bx == 512){
    float* red = smem;
    for (int n = tid; n < 2048; n += 256){
      bias[n] = (n < 1024) ? (bihf[n] + bhhf[n]) : (bihb[n-1024] + bhhb[n-1024]);
    }
    const int cur = tid & 15, part = tid >> 4;
    float s = 0.f;
    for (int k = part*32; k < part*32 + 32; k++) s += fcw[cur*512 + k] * wdp[k];
    red[tid] = s;
    __syncthreads();
    if (tid < 16){
      float t = 0.f;
      #pragma unroll
      for (int p = 0; p < 16; p++) t += red[p*16 + tid];
      wfc[tid] = t;
    }
    return;
  }
  {
    const int row = bx*4 + (tid >> 6);
    const int lane = tid & 63;
    const float* src = (row < 1024) ? (whhf + (size_t)row*256)
                                    : (whhb + (size_t)(row-1024)*256);
    f32x4 v = *(const f32x4*)(src + lane*4);
    float m = fmaxf(fmaxf(fabsf(v[0]), fabsf(v[1])), fmaxf(fabsf(v[2]), fabsf(v[3])));
    #pragma unroll
    for (int d = 1; d < 64; d <<= 1) m = fmaxf(m, __shfl_xor(m, d, 64));
    float inv = 127.f / (m + 1e-30f);
    u32 pack = 0;
    #pragma unroll
    for (int e = 0; e < 4; e++){
      int q = (int)rintf(v[e]*inv);
      q = q > 127 ? 127 : (q < -127 ? -127 : q);
      pack |= ((u32)(u8)(s8)q) << (8*e);
    }
    const int dir = row >> 10, n = row & 1023;
    const int g = n >> 8, j = n & 255, w2 = j >> 4, lr2 = j & 15;
    const int kk = lane >> 4, lq2 = (lane >> 2) & 3, e4 = lane & 3;
    u32* wq32 = (u32*)wq;
    wq32[dir*65536 + (((g*16 + w2)*4 + kk)*64 + lq2*16 + lr2)*4 + e4] = pack;
    if (lane == 0) sc2[row] = m * (1.f/16129.f);
  }
}

// ---------------- K2: gi = bf16(feat @ wih^T + bias), double-buffered LDS ----------------
__global__ __launch_bounds__(256) void k2_gemm(
    const u16* __restrict__ featp, const u16* __restrict__ wihp,
    const float* __restrict__ bias, u16* __restrict__ gi)
{
  const int m0 = blockIdx.y*128, n0 = blockIdx.x*128;
  const int tid = threadIdx.x, wv = tid>>6, lane = tid&63;
  const int lr = lane & 15, lq = lane >> 4;
  const int wm = (wv>>1)*64, wn = (wv&1)*64;
  __shared__ u16 As[2][4096], Bs[2][4096];
  f32x4 acc[4][4];
  #pragma unroll
  for (int a=0;a<4;a++)
    #pragma unroll
    for (int c=0;c<4;c++) acc[a][c] = (f32x4){0.f,0.f,0.f,0.f};

  #define K2_STAGE(BUF, K0) { \
    _Pragma("unroll") \
    for (int i = 0; i < 2; i++){ \
      int c = i*4 + wv; \
      gld_lds16(featp + (size_t)(m0 + c*16 + (lane>>2))*416 + (K0) + (lane&3)*8, &As[BUF][c*512]); \
      gld_lds16(wihp  + (size_t)(n0 + c*16 + (lane>>2))*416 + (K0) + (lane&3)*8, &Bs[BUF][c*512]); \
    } }

  K2_STAGE(0, 0);
  __syncthreads();
  int buf = 0;
  for (int ki = 0; ki < 13; ki++){
    if (ki < 12) K2_STAGE(buf^1, (ki+1)*32);
    short8 af[4], bfr[4];
    #pragma unroll
    for (int mt=0; mt<4; mt++) af[mt]  = *(const short8*)(&As[buf][0] + (wm + mt*16 + lr)*32 + lq*8);
    #pragma unroll
    for (int nt=0; nt<4; nt++) bfr[nt] = *(const short8*)(&Bs[buf][0] + (wn + nt*16 + lr)*32 + lq*8);
    #pragma unroll
    for (int mt=0; mt<4; mt++)
      #pragma unroll
      for (int nt=0; nt<4; nt++)
        acc[mt][nt] = __builtin_amdgcn_mfma_f32_16x16x32_bf16(af[mt], bfr[nt], acc[mt][nt], 0,0,0);
    __syncthreads();
    buf ^= 1;
  }
  #undef K2_STAGE
  #pragma unroll
  for (int nt=0; nt<4; nt++){
    float bv = bias[n0 + wn + nt*16 + lr];
    #pragma unroll
    for (int mt=0; mt<4; mt++)
      #pragma unroll
      for (int r=0; r<4; r++)
        gi[(size_t)(m0 + wm + mt*16 + lq*4 + r)*2048 + n0 + wn + nt*16 + lr]
            = f2bf(acc[mt][nt][r] + bv);
  }
}

// ---------------- K3: recurrent BiLSTM, 64 blocks x 512 thr, all-VGPR weights ----------------
__global__ __launch_bounds__(512, 2) void k3_lstm(
    const s8* __restrict__ wq, const float* __restrict__ sc2,
    const u16* __restrict__ gi, u16* __restrict__ hcat)
{
  const int dir = blockIdx.x >> 5;
  const int bb  = (blockIdx.x & 31) * 2;
  const int tid = threadIdx.x;
  const int w = tid >> 6, lane = tid & 63;
  const int lr = lane & 15, lq = lane >> 4;
  const int cb = tid >> 8, cj = tid & 255;

  __shared__ s8 Hs[2][4096];
  __shared__ float xbuf[2048];

  const s8* wqd = wq + dir*262144;
  int4v bq[2][4][4];
  #pragma unroll
  for (int sl = 0; sl < 2; sl++)
    #pragma unroll
    for (int g = 0; g < 4; g++)
      #pragma unroll
      for (int kk = 0; kk < 4; kk++)
        bq[sl][g][kk] = *(const int4v*)(wqd + (((((g*16 + 2*w + sl)*4 + kk)*64) + lane) << 4));

  float scl[4];
  #pragma unroll
  for (int g = 0; g < 4; g++) scl[g] = sc2[dir*1024 + g*256 + cj];

  *(uint2*)&Hs[0][tid*8] = (uint2){0u,0u};
  *(uint2*)&Hs[1][tid*8] = (uint2){0u,0u};

  float cst = 0.f;
  const ptrdiff_t dstep = dir ? -(ptrdiff_t)131072 : (ptrdiff_t)131072;
  const u16* g0 = gi + (size_t)((dir ? 511 : 0)*64 + bb + cb)*2048 + dir*1024 + cj;
  u32 gcur[4], gn1[4], gn2[4];
  #pragma unroll
  for (int g = 0; g < 4; g++) gcur[g] = g0[g*256];
  const u16* g1 = g0 + dstep;
  #pragma unroll
  for (int g = 0; g < 4; g++) gn1[g] = g1[g*256];
  const u16* gpref = g1;
  __syncthreads();

  #pragma unroll 1
  for (int t = 0; t < 512; t++){
    const int s = dir ? (511 - t) : t;
    if (t + 2 < 512) gpref += dstep;
    #pragma unroll
    for (int g = 0; g < 4; g++) gn2[g] = gpref[g*256];
    const s8* hb = Hs[t & 1];
    int4v aq[4];
    #pragma unroll
    for (int kk = 0; kk < 4; kk++)
      aq[kk] = *(const int4v*)(hb + lr*256 + ((kk*64 + lq*16) ^ (lr << 4)));
    int4v acc[2][4];
    #pragma unroll
    for (int sl = 0; sl < 2; sl++)
      #pragma unroll
      for (int g = 0; g < 4; g++) acc[sl][g] = (int4v){0,0,0,0};
    __builtin_amdgcn_s_setprio(1);
    #pragma unroll
    for (int kk = 0; kk < 4; kk++)
      #pragma unroll
      for (int sl = 0; sl < 2; sl++)
        #pragma unroll
        for (int g = 0; g < 4; g++)
          acc[sl][g] = __builtin_amdgcn_mfma_i32_16x16x64_i8(aq[kk], bq[sl][g][kk], acc[sl][g], 0,0,0);
    __builtin_amdgcn_s_setprio(0);
    if (lq == 0){
      #pragma unroll
      for (int sl = 0; sl < 2; sl++){
        const int j = (2*w + sl)*16 + lr;
        #pragma unroll
        for (int r = 0; r < 2; r++){
          f32x4 v = (f32x4){(float)acc[sl][0][r], (float)acc[sl][1][r],
                            (float)acc[sl][2][r], (float)acc[sl][3][r]};
          *(f32x4*)&xbuf[(r*256 + j)*4] = v;
        }
      }
    }
    bar_l();
    f32x4 p = *(const f32x4*)&xbuf[tid*4];
    float g4[4];
    #pragma unroll
    for (int g = 0; g < 4; g++) g4[g] = bf2f((u16)gcur[g]) + p[g]*scl[g];
    float iv = sigf(g4[0]), fv = sigf(g4[1]);
    float gg = tanh_f(g4[2]), ov = sigf(g4[3]);
    float c = fv*cst + iv*gg;
    cst = c;
    float h = ov * tanh_f(c);
    hcat[(size_t)(s*64 + bb + cb)*512 + dir*256 + cj] = f2bf(h);
    Hs[(t + 1) & 1][cb*256 + (cj ^ (cb << 4))] = (s8)(int)rintf(h * 127.f);
    #pragma unroll
    for (int g = 0; g < 4; g++){ gcur[g] = gn1[g]; gn1[g] = gn2[g]; }
    bar_l();
  }
}

// ---------------- K4: P = Hcat @ fc_w^T + fc_b + lm*wfc  [32768 x 16] fp32 ----------------
__global__ __launch_bounds__(256) void k4_fc(
    const u16* __restrict__ hcat, const float* __restrict__ fcw, const float* __restrict__ fcb,
    const float* __restrict__ lmp, const float* __restrict__ wfc, float* __restrict__ Pout)
{
  const int wv = threadIdx.x >> 6, lane = threadIdx.x & 63;
  const int lr = lane & 15, lq = lane >> 4;
  const int mt = blockIdx.x*4 + wv;
  short8 bfr[16];
  #pragma unroll
  for (int kk = 0; kk < 16; kk++){
    const float* wr = fcw + (size_t)lr*512 + kk*32 + lq*8;
    f32x4 w0 = *(const f32x4*)wr;
    f32x4 w1 = *(const f32x4*)(wr + 4);
    short8 sv;
    #pragma unroll
    for (int e = 0; e < 4; e++){ sv[e] = (short)f2bf(w0[e]); sv[4+e] = (short)f2bf(w1[e]); }
    bfr[kk] = sv;
  }
  f32x4 acc = (f32x4){0.f,0.f,0.f,0.f};
  #pragma unroll
  for (int kk = 0; kk < 16; kk++){
    short8 af = *(const short8*)(hcat + (size_t)(mt*16 + lr)*512 + kk*32 + lq*8);
    acc = __builtin_amdgcn_mfma_f32_16x16x32_bf16(af, bfr[kk], acc, 0,0,0);
  }
  const int cur = lr;
  float fb = fcb[cur];
  float wf = wfc[cur];
  #pragma unroll
  for (int r = 0; r < 4; r++){
    int m = mt*16 + lq*4 + r;
    int b = m & 63, s = m >> 6;
    float lmv = lmp[b*512 + s];
    Pout[(size_t)m*16 + cur] = acc[r] + fb + lmv*wf;
  }
}

// ---------------- K5: Viterbi — shuffle-free (replicated delta + readlane) ----------------
__global__ __launch_bounds__(64) void k5_vit(
    const float* __restrict__ Pg, const float* __restrict__ Am,
    float* __restrict__ dout, float* __restrict__ dl, u8* __restrict__ psi)
{
  const int b = blockIdx.x, lane = threadIdx.x;
  const int cur = lane & 15;
  float Ar[16];
  #pragma unroll
  for (int p = 0; p < 16; p++) Ar[p] = Am[p*16 + cur];
  float dreg[16];
  {
    float v0 = Pg[(size_t)b*16 + cur];
    if (lane < 16) dl[(size_t)b*16 + cur] = v0;
    #pragma unroll
    for (int c = 0; c < 16; c++) dreg[c] = rdlane_f(v0, c);
  }

#define FSTEP(X, S) { \
    float v_[16]; \
    _Pragma("unroll") \
    for (int p = 0; p < 16; p++) v_[p] = dreg[p] + Ar[p]; \
    float m1[8]; int i1[8]; \
    _Pragma("unroll") \
    for (int k = 0; k < 8; k++){ bool c_ = v_[2*k] >= v_[2*k+1]; \
      m1[k] = c_ ? v_[2*k] : v_[2*k+1]; i1[k] = c_ ? 2*k : 2*k+1; } \
    float m2[4]; int i2[4]; \
    _Pragma("unroll") \
    for (int k = 0; k < 4; k++){ bool c_ = m1[2*k] >= m1[2*k+1]; \
      m2[k] = c_ ? m1[2*k] : m1[2*k+1]; i2[k] = c_ ? i1[2*k] : i1[2*k+1]; } \
    float m3[2]; int i3[2]; \
    _Pragma("unroll") \
    for (int k = 0; k < 2; k++){ bool c_ = m2[2*k] >= m2[2*k+1]; \
      m3[k] = c_ ? m2[2*k] : m2[2*k+1]; i3[k] = c_ ? i2[2*k] : i2[2*k+1]; } \
    bool cf_ = m3[0] >= m3[1]; \
    float best = (cf_ ? m3[0] : m3[1]) + (X); \
    int bi = cf_ ? i3[0] : i3[1]; \
    if (lane < 16){ \
      dl[(size_t)((S)*64 + b)*16 + cur] = best; \
      psi[(size_t)((S)*64 + b)*16 + cur] = (u8)bi; \
    } \
    _Pragma("unroll") \
    for (int c = 0; c < 16; c++) dreg[c] = rdlane_f(best, c); \
  }

  float x0 = Pg[(size_t)(1*64 + b)*16 + cur];
  float x1 = Pg[(size_t)(2*64 + b)*16 + cur];
  float x2 = Pg[(size_t)(3*64 + b)*16 + cur];
  float x3 = Pg[(size_t)(4*64 + b)*16 + cur];
  for (int s = 1; s < 512; s += 4){
    FSTEP(x0, s);
    if (s + 4 < 512) x0 = Pg[(size_t)((s+4)*64 + b)*16 + cur];
    if (s + 1 < 512) FSTEP(x1, s+1);
    if (s + 5 < 512) x1 = Pg[(size_t)((s+5)*64 + b)*16 + cur];
    if (s + 2 < 512) FSTEP(x2, s+2);
    if (s + 6 < 512) x2 = Pg[(size_t)((s+6)*64 + b)*16 + cur];
    if (s + 3 < 512) FSTEP(x3, s+3);
    if (s + 7 < 512) x3 = Pg[(size_t)((s+7)*64 + b)*16 + cur];
  }
#undef FSTEP

  float bv = dreg[0]; int bix = 0;
  #pragma unroll
  for (int c = 1; c < 16; c++){ if (dreg[c] > bv){ bv = dreg[c]; bix = c; } }
  int tag = bix;
  float score = bv;
  if (lane == 0) dout[b*512 + 511] = (float)tag;

#define BSTEP(PV, DV, T) { \
    int prev = __builtin_amdgcn_readlane((PV), tag); \
    score += rdlane_f((DV), prev); \
    if (lane == 0) dout[b*512 + (T)] = (float)prev; \
    tag = prev; }

  int   p0 = 0, p1 = 0, p2 = 0, p3 = 0;
  float d0 = 0.f, d1 = 0.f, d2 = 0.f, d3 = 0.f;
  if (lane < 16){
    p0 = psi[(size_t)(511*64 + b)*16 + lane]; d0 = dl[(size_t)(510*64 + b)*16 + lane];
    p1 = psi[(size_t)(510*64 + b)*16 + lane]; d1 = dl[(size_t)(509*64 + b)*16 + lane];
    p2 = psi[(size_t)(509*64 + b)*16 + lane]; d2 = dl[(size_t)(508*64 + b)*16 + lane];
    p3 = psi[(size_t)(508*64 + b)*16 + lane]; d3 = dl[(size_t)(507*64 + b)*16 + lane];
  }
  for (int t = 510; t >= 0; t -= 4){
    BSTEP(p0, d0, t);
    if (t - 4 >= 0 && lane < 16){
      p0 = psi[(size_t)((t-3)*64 + b)*16 + lane]; d0 = dl[(size_t)((t-4)*64 + b)*16 + lane];
    }
    if (t - 1 >= 0) BSTEP(p1, d1, t-1);
    if (t - 5 >= 0 && lane < 16){
      p1 = psi[(size_t)((t-4)*64 + b)*16 + lane]; d1 = dl[(size_t)((t-5)*64 + b)*16 + lane];
    }
    if (t - 2 >= 0) BSTEP(p2, d2, t-2);
    if (t - 6 >= 0 && lane < 16){
      p2 = psi[(size_t)((t-5)*64 + b)*16 + lane]; d2 = dl[(size_t)((t-6)*64 + b)*16 + lane];
    }
    if (t - 3 >= 0) BSTEP(p3, d3, t-3);
    if (t - 7 >= 0 && lane < 16){
      p3 = psi[(size_t)((t-6)*64 + b)*16 + lane]; d3 = dl[(size_t)((t-7)*64 + b)*16 + lane];
    }
  }
#undef BSTEP
  if (lane == 0) dout[32768 + b] = score;
}

// ---------------- launcher ----------------
extern "C" void kernel_launch(void* const* d_in, const int* in_sizes, int n_in,
                              void* d_out, int out_size, void* d_ws, size_t ws_size,
                              hipStream_t stream)
{
  (void)in_sizes; (void)n_in; (void)out_size;
  if (ws_size < REQUIRED) return;

  const int*   X    = (const int*)d_in[0];
  const float* lm   = (const float*)d_in[1];
  const int*   tg   = (const int*)d_in[2];
  const int*   ch   = (const int*)d_in[3];
  const float* etab = (const float*)d_in[4];
  const float* ttab = (const float*)d_in[5];
  const float* ctab = (const float*)d_in[6];
  const float* cw   = (const float*)d_in[7];
  const float* cb   = (const float*)d_in[8];
  const float* wihf = (const float*)d_in[9];
  const float* whhf = (const float*)d_in[10];
  const float* bihf = (const float*)d_in[11];
  const float* bhhf = (const float*)d_in[12];
  const float* wihb = (const float*)d_in[13];
  const float* whhb = (const float*)d_in[14];
  const float* bihb = (const float*)d_in[15];
  const float* bhhb = (const float*)d_in[16];
  const float* fcw  = (const float*)d_in[17];
  const float* fcb  = (const float*)d_in[18];
  const float* Am   = (const float*)d_in[19];
  const float* wdp  = (const float*)d_in[20];

  char* ws = (char*)d_ws;
  u16*   gi   = (u16*)(ws + OFF_GI);
  u16*   feat = (u16*)(ws + OFF_B);
  u16*   hcat = (u16*)(ws + OFF_B);
  u16*   wih  = (u16*)(ws + OFF_WIH);
  s8*    wq   = (s8*)(ws + OFF_WQ);
  float* sc2  = (float*)(ws + OFF_SC);
  float* Pg   = (float*)(ws + OFF_P);
  float* dlt  = (float*)(ws + OFF_DL);
  u8*    psi  = (u8*)(ws + OFF_PSI);
  float* bias = (float*)(ws + OFF_BIAS);
  float* wfc  = (float*)(ws + OFF_WFC);
  float* dout = (float*)d_out;

  k01_fused<<<5633, 256, 0, stream>>>(X, tg, ch, etab, ttab, ctab, cw, cb, feat,
                                      whhf, whhb, wq, sc2,
                                      bihf, bhhf, bihb, bhhb, fcw, wdp, bias, wfc,
                                      wihf, wihb, wih);
  k2_gemm<<<dim3(16, 256), 256, 0, stream>>>(feat, wih, bias, gi);
  k3_lstm<<<64, 512, 0, stream>>>(wq, sc2, gi, hcat);
  k4_fc<<<512, 256, 0, stream>>>(hcat, fcw, fcb, lm, wfc, Pg);
  k5_vit<<<64, 64, 0, stream>>>(Pg, Am, dout, dlt, psi);
}

// Round 16
// 963.723 us; speedup vs baseline: 1.4139x; 1.1121x over previous
//
#include <hip/hip_runtime.h>

// BiLSTM-CRF on MI355X. Round 16: conv rewritten as MFMA GEMM + maxpool
// (bf16, XOR-swizzled LDS), fused kernel block map:
//   [0,2048)    conv-GEMM blocks (b=bid>>5, sg=bid&31; 256 positions each)
//   [2048,4096) copy blocks: embed/tag/pad rows of feat
//   [4096,6657) k0 blocks: W_hh quantize | bias/wfc | W_ih pack
// K2 (dbuf), K3 (500us), K4, K5 frozen.

#define DEV __device__ __forceinline__
typedef unsigned short u16;
typedef unsigned int   u32;
typedef unsigned char  u8;
typedef signed char    s8;
using short8  = __attribute__((ext_vector_type(8))) short;
using f32x4   = __attribute__((ext_vector_type(4))) float;
using int4v   = __attribute__((ext_vector_type(4))) int;

DEV float bf2f(u16 u){ union{u32 i; float f;} v; v.i = ((u32)u)<<16; return v.f; }
DEV u16 f2bf(float f){ u32 x = __float_as_uint(f); return (u16)((x + 0x7fffu + ((x>>16)&1u)) >> 16); }
DEV u32 pk2(float a, float b){ return (u32)f2bf(a) | ((u32)f2bf(b) << 16); }
DEV float sigf(float x){ return __builtin_amdgcn_rcpf(1.f + __expf(-x)); }
DEV float tanh_f(float x){ return 1.f - 2.f*__builtin_amdgcn_rcpf(__expf(2.f*x) + 1.f); }
DEV float rdlane_f(float v, int l){
  return __uint_as_float(__builtin_amdgcn_readlane(__float_as_uint(v), l));
}

typedef __attribute__((address_space(1))) const u32 GU;
typedef __attribute__((address_space(3))) u32 LU;
DEV void gld_lds16(const void* g, void* l){
  __builtin_amdgcn_global_load_lds((GU*)g, (LU*)l, 16, 0, 0);
}
DEV void bar_l(){
  __builtin_amdgcn_sched_barrier(0);
  asm volatile("s_waitcnt lgkmcnt(0)" ::: "memory");
  __builtin_amdgcn_s_barrier();
  __builtin_amdgcn_sched_barrier(0);
}

// ---------------- ws layout (aliased; total ~170MB) ----------------
static const size_t OFF_GI   = 0;
static const size_t OFF_P    = 0;
static const size_t OFF_DL   = OFF_P  + (size_t)32768*16*4;
static const size_t OFF_PSI  = OFF_DL + (size_t)32768*16*4;
static const size_t OFF_B    = (size_t)134217728;
static const size_t OFF_WIH  = OFF_B    + (size_t)33554432;
static const size_t OFF_WQ   = OFF_WIH  + (size_t)1703936;   // 512KB i8 frags
static const size_t OFF_SC   = OFF_WQ   + (size_t)524288;    // 8KB scales
static const size_t OFF_BIAS = OFF_SC   + 8192;
static const size_t OFF_WFC  = OFF_BIAS + 8192;
static const size_t REQUIRED = OFF_WFC  + 256;

// LDS byte-offset helpers (XOR swizzle within 128B-multiple row strides)
#define CEB(r, byo) ((r)*128 + ((byo) ^ (((r)&7)<<4)))
#define WBB(r, byo) (33024 + (r)*384 + ((byo) ^ (((r)&7)<<4)))

// ---------------- K01: fused conv-GEMM / feat-copy / k0 ----------------
__global__ __launch_bounds__(256) void k01_fused(
    const int* __restrict__ X, const int* __restrict__ tg, const int* __restrict__ ch,
    const float* __restrict__ etab, const float* __restrict__ ttab, const float* __restrict__ ctab,
    const float* __restrict__ cw, const float* __restrict__ cb, u16* __restrict__ feat,
    const float* __restrict__ whhf, const float* __restrict__ whhb,
    s8* __restrict__ wq, float* __restrict__ sc2,
    const float* bihf, const float* bhhf, const float* bihb, const float* bhhb,
    const float* fcw, const float* wdp, float* bias, float* wfc,
    const float* __restrict__ wihf, const float* __restrict__ wihb, u16* __restrict__ wih)
{
  __shared__ float smemf[14400];   // 57600B: ce rows [258][128B] | B [64][384B]
  char* sm = (char*)smemf;
  const int tid = threadIdx.x;
  const int bid = blockIdx.x;

  if (bid < 2048){
    // ---------- conv-GEMM block: 256 positions (16 s) of batch b ----------
    const int b = bid >> 5, sg = bid & 31;
    // stage B weights [cc=64][k'=192] bf16 (k' = dc*64 + ce; pads zero)
    for (int i = tid; i < 6144; i += 256){
      int row = i/96, pair = i - row*96;
      int k0 = pair*2;
      int dc = k0 >> 6, ce = k0 & 63;
      float v0 = 0.f, v1 = 0.f;
      if (row < 50 && ce < 50){
        v0 = cw[row*150 + ce*3 + dc];
        if (ce + 1 < 50) v1 = cw[row*150 + (ce+1)*3 + dc];
      }
      *(u32*)(sm + WBB(row, pair*4)) = pk2(v0, v1);
    }
    // stage ce rows [258][64] bf16 (row r -> p_local = sg*256 - 1 + r)
    for (int i = tid; i < 8256; i += 256){
      int row = i >> 5, pair = i & 31;
      int ce0 = pair*2;
      float v0 = 0.f, v1 = 0.f;
      int pl = sg*256 - 1 + row;
      if (pl >= 0 && pl < 8192 && ce0 < 50){
        int ci = ch[b*8192 + pl];
        float2 f = *(const float2*)(ctab + (size_t)ci*50 + ce0);
        v0 = f.x; v1 = f.y;
      }
      *(u32*)(sm + CEB(row, pair*4)) = pk2(v0, v1);
    }
    __syncthreads();

    const int wv = tid >> 6, lane = tid & 63;
    const int lr = lane & 15, lq = lane >> 4;
    f32x4 acc[4][4];
    #pragma unroll
    for (int mt = 0; mt < 4; mt++)
      #pragma unroll
      for (int nt = 0; nt < 4; nt++) acc[mt][nt] = (f32x4){0.f,0.f,0.f,0.f};
    #pragma unroll
    for (int kk = 0; kk < 6; kk++){
      const int kp = kk*32 + lq*8;
      const int dc = kp >> 6, ce8 = kp & 63;
      short8 bfr[4], af[4];
      #pragma unroll
      for (int nt = 0; nt < 4; nt++)
        bfr[nt] = *(const short8*)(sm + WBB(nt*16 + lr, kp*2));
      #pragma unroll
      for (int mt = 0; mt < 4; mt++){
        const int pos = (wv*4 + mt)*16 + lr;
        af[mt] = *(const short8*)(sm + CEB(pos + dc, ce8*2));
      }
      #pragma unroll
      for (int mt = 0; mt < 4; mt++)
        #pragma unroll
        for (int nt = 0; nt < 4; nt++)
          acc[mt][nt] = __builtin_amdgcn_mfma_f32_16x16x32_bf16(af[mt], bfr[nt], acc[mt][nt], 0,0,0);
    }
    // maxpool over w (the 16 rows of each m-tile) + bias + store
    #pragma unroll
    for (int mt = 0; mt < 4; mt++){
      const int s = sg*16 + wv*4 + mt;
      #pragma unroll
      for (int nt = 0; nt < 4; nt++){
        float m = fmaxf(fmaxf(acc[mt][nt][0], acc[mt][nt][1]),
                        fmaxf(acc[mt][nt][2], acc[mt][nt][3]));
        m = fmaxf(m, __shfl_xor(m, 16, 64));
        m = fmaxf(m, __shfl_xor(m, 32, 64));
        const int cc = nt*16 + lr;
        if (lq == 0 && cc < 50)
          feat[(size_t)(s*64 + b)*416 + 350 + cc] = f2bf(m + cb[cc]);
      }
    }
    return;
  }

  if (bid < 4096){
    // ---------- copy blocks: embed/tag/pad rows of feat ----------
    const int cid = bid - 2048;           // 0..2047, 16 rows each
    const int w = tid >> 6, lane = tid & 63;
    #pragma unroll
    for (int r = 0; r < 4; r++){
      const int m = cid*16 + w*4 + r;     // row = s*64+b
      const int s = m >> 6, b = m & 63;
      const int xi = X[b*512 + s];
      const int ti = tg[b*512 + s];
      u32* dst = (u32*)feat + (size_t)m*208;
      #pragma unroll
      for (int pass = 0; pass < 3; pass++){
        int word = pass*64 + lane;
        if (word < 150){
          float2 f = *(const float2*)(etab + (size_t)xi*300 + word*2);
          dst[word] = pk2(f.x, f.y);
        } else if (word < 175){
          float2 f = *(const float2*)(ttab + (size_t)ti*50 + (word-150)*2);
          dst[word] = pk2(f.x, f.y);
        } else if (word < 183){
          dst[200 + word - 175] = 0u;
        }
      }
    }
    return;
  }

  // ---------- k0 blocks ----------
  const int bx = bid - 4096;              // 0..2560
  if (bx > 512){
    const int n = bx - 513;
    const float* src = (n < 1024) ? (wihf + (size_t)n*400) : (wihb + (size_t)(n-1024)*400);
    u32* dst = (u32*)(wih + (size_t)n*416);
    if (tid < 208){
      int j = tid*2;
      u32 v = 0u;
      if (j < 400){
        float2 f = *(const float2*)(src + j);
        v = pk2(f.x, f.y);
      }
      dst[tid] = v;
    }
    return;
  }
  if (bx == 512){
    float* red = smemf;
    for (int n = tid; n < 2048; n += 256){
      bias[n] = (n < 1024) ? (bihf[n] + bhhf[n]) : (bihb[n-1024] + bhhb[n-1024]);
    }
    const int cur = tid & 15, part = tid >> 4;
    float s = 0.f;
    for (int k = part*32; k < part*32 + 32; k++) s += fcw[cur*512 + k] * wdp[k];
    red[tid] = s;
    __syncthreads();
    if (tid < 16){
      float t = 0.f;
      #pragma unroll
      for (int p = 0; p < 16; p++) t += red[p*16 + tid];
      wfc[tid] = t;
    }
    return;
  }
  {
    const int row = bx*4 + (tid >> 6);
    const int lane = tid & 63;
    const float* src = (row < 1024) ? (whhf + (size_t)row*256)
                                    : (whhb + (size_t)(row-1024)*256);
    f32x4 v = *(const f32x4*)(src + lane*4);
    float m = fmaxf(fmaxf(fabsf(v[0]), fabsf(v[1])), fmaxf(fabsf(v[2]), fabsf(v[3])));
    #pragma unroll
    for (int d = 1; d < 64; d <<= 1) m = fmaxf(m, __shfl_xor(m, d, 64));
    float inv = 127.f / (m + 1e-30f);
    u32 pack = 0;
    #pragma unroll
    for (int e = 0; e < 4; e++){
      int q = (int)rintf(v[e]*inv);
      q = q > 127 ? 127 : (q < -127 ? -127 : q);
      pack |= ((u32)(u8)(s8)q) << (8*e);
    }
    const int dir = row >> 10, n = row & 1023;
    const int g = n >> 8, j = n & 255, w2 = j >> 4, lr2 = j & 15;
    const int kk = lane >> 4, lq2 = (lane >> 2) & 3, e4 = lane & 3;
    u32* wq32 = (u32*)wq;
    wq32[dir*65536 + (((g*16 + w2)*4 + kk)*64 + lq2*16 + lr2)*4 + e4] = pack;
    if (lane == 0) sc2[row] = m * (1.f/16129.f);
  }
}
#undef CEB
#undef WBB

// ---------------- K2: gi = bf16(feat @ wih^T + bias), double-buffered LDS ----------------
__global__ __launch_bounds__(256) void k2_gemm(
    const u16* __restrict__ featp, const u16* __restrict__ wihp,
    const float* __restrict__ bias, u16* __restrict__ gi)
{
  const int m0 = blockIdx.y*128, n0 = blockIdx.x*128;
  const int tid = threadIdx.x, wv = tid>>6, lane = tid&63;
  const int lr = lane & 15, lq = lane >> 4;
  const int wm = (wv>>1)*64, wn = (wv&1)*64;
  __shared__ u16 As[2][4096], Bs[2][4096];
  f32x4 acc[4][4];
  #pragma unroll
  for (int a=0;a<4;a++)
    #pragma unroll
    for (int c=0;c<4;c++) acc[a][c] = (f32x4){0.f,0.f,0.f,0.f};

  #define K2_STAGE(BUF, K0) { \
    _Pragma("unroll") \
    for (int i = 0; i < 2; i++){ \
      int c = i*4 + wv; \
      gld_lds16(featp + (size_t)(m0 + c*16 + (lane>>2))*416 + (K0) + (lane&3)*8, &As[BUF][c*512]); \
      gld_lds16(wihp  + (size_t)(n0 + c*16 + (lane>>2))*416 + (K0) + (lane&3)*8, &Bs[BUF][c*512]); \
    } }

  K2_STAGE(0, 0);
  __syncthreads();
  int buf = 0;
  for (int ki = 0; ki < 13; ki++){
    if (ki < 12) K2_STAGE(buf^1, (ki+1)*32);
    short8 af[4], bfr[4];
    #pragma unroll
    for (int mt=0; mt<4; mt++) af[mt]  = *(const short8*)(&As[buf][0] + (wm + mt*16 + lr)*32 + lq*8);
    #pragma unroll
    for (int nt=0; nt<4; nt++) bfr[nt] = *(const short8*)(&Bs[buf][0] + (wn + nt*16 + lr)*32 + lq*8);
    #pragma unroll
    for (int mt=0; mt<4; mt++)
      #pragma unroll
      for (int nt=0; nt<4; nt++)
        acc[mt][nt] = __builtin_amdgcn_mfma_f32_16x16x32_bf16(af[mt], bfr[nt], acc[mt][nt], 0,0,0);
    __syncthreads();
    buf ^= 1;
  }
  #undef K2_STAGE
  #pragma unroll
  for (int nt=0; nt<4; nt++){
    float bv = bias[n0 + wn + nt*16 + lr];
    #pragma unroll
    for (int mt=0; mt<4; mt++)
      #pragma unroll
      for (int r=0; r<4; r++)
        gi[(size_t)(m0 + wm + mt*16 + lq*4 + r)*2048 + n0 + wn + nt*16 + lr]
            = f2bf(acc[mt][nt][r] + bv);
  }
}

// ---------------- K3: recurrent BiLSTM, 64 blocks x 512 thr, all-VGPR weights ----------------
__global__ __launch_bounds__(512, 2) void k3_lstm(
    const s8* __restrict__ wq, const float* __restrict__ sc2,
    const u16* __restrict__ gi, u16* __restrict__ hcat)
{
  const int dir = blockIdx.x >> 5;
  const int bb  = (blockIdx.x & 31) * 2;
  const int tid = threadIdx.x;
  const int w = tid >> 6, lane = tid & 63;
  const int lr = lane & 15, lq = lane >> 4;
  const int cb = tid >> 8, cj = tid & 255;

  __shared__ s8 Hs[2][4096];
  __shared__ float xbuf[2048];

  const s8* wqd = wq + dir*262144;
  int4v bq[2][4][4];
  #pragma unroll
  for (int sl = 0; sl < 2; sl++)
    #pragma unroll
    for (int g = 0; g < 4; g++)
      #pragma unroll
      for (int kk = 0; kk < 4; kk++)
        bq[sl][g][kk] = *(const int4v*)(wqd + (((((g*16 + 2*w + sl)*4 + kk)*64) + lane) << 4));

  float scl[4];
  #pragma unroll
  for (int g = 0; g < 4; g++) scl[g] = sc2[dir*1024 + g*256 + cj];

  *(uint2*)&Hs[0][tid*8] = (uint2){0u,0u};
  *(uint2*)&Hs[1][tid*8] = (uint2){0u,0u};

  float cst = 0.f;
  const ptrdiff_t dstep = dir ? -(ptrdiff_t)131072 : (ptrdiff_t)131072;
  const u16* g0 = gi + (size_t)((dir ? 511 : 0)*64 + bb + cb)*2048 + dir*1024 + cj;
  u32 gcur[4], gn1[4], gn2[4];
  #pragma unroll
  for (int g = 0; g < 4; g++) gcur[g] = g0[g*256];
  const u16* g1 = g0 + dstep;
  #pragma unroll
  for (int g = 0; g < 4; g++) gn1[g] = g1[g*256];
  const u16* gpref = g1;
  __syncthreads();

  #pragma unroll 1
  for (int t = 0; t < 512; t++){
    const int s = dir ? (511 - t) : t;
    if (t + 2 < 512) gpref += dstep;
    #pragma unroll
    for (int g = 0; g < 4; g++) gn2[g] = gpref[g*256];
    const s8* hb = Hs[t & 1];
    int4v aq[4];
    #pragma unroll
    for (int kk = 0; kk < 4; kk++)
      aq[kk] = *(const int4v*)(hb + lr*256 + ((kk*64 + lq*16) ^ (lr << 4)));
    int4v acc[2][4];
    #pragma unroll
    for (int sl = 0; sl < 2; sl++)
      #pragma unroll
      for (int g = 0; g < 4; g++) acc[sl][g] = (int4v){0,0,0,0};
    __builtin_amdgcn_s_setprio(1);
    #pragma unroll
    for (int kk = 0; kk < 4; kk++)
      #pragma unroll
      for (int sl = 0; sl < 2; sl++)
        #pragma unroll
        for (int g = 0; g < 4; g++)
          acc[sl][g] = __builtin_amdgcn_mfma_i32_16x16x64_i8(aq[kk], bq[sl][g][kk], acc[sl][g], 0,0,0);
    __builtin_amdgcn_s_setprio(0);
    if (lq == 0){
      #pragma unroll
      for (int sl = 0; sl < 2; sl++){
        const int j = (2*w + sl)*16 + lr;
        #pragma unroll
        for (int r = 0; r < 2; r++){
          f32x4 v = (f32x4){(float)acc[sl][0][r], (float)acc[sl][1][r],
                            (float)acc[sl][2][r], (float)acc[sl][3][r]};
          *(f32x4*)&xbuf[(r*256 + j)*4] = v;
        }
      }
    }
    bar_l();
    f32x4 p = *(const f32x4*)&xbuf[tid*4];
    float g4[4];
    #pragma unroll
    for (int g = 0; g < 4; g++) g4[g] = bf2f((u16)gcur[g]) + p[g]*scl[g];
    float iv = sigf(g4[0]), fv = sigf(g4[1]);
    float gg = tanh_f(g4[2]), ov = sigf(g4[3]);
    float c = fv*cst + iv*gg;
    cst = c;
    float h = ov * tanh_f(c);
    hcat[(size_t)(s*64 + bb + cb)*512 + dir*256 + cj] = f2bf(h);
    Hs[(t + 1) & 1][cb*256 + (cj ^ (cb << 4))] = (s8)(int)rintf(h * 127.f);
    #pragma unroll
    for (int g = 0; g < 4; g++){ gcur[g] = gn1[g]; gn1[g] = gn2[g]; }
    bar_l();
  }
}

// ---------------- K4: P = Hcat @ fc_w^T + fc_b + lm*wfc  [32768 x 16] fp32 ----------------
__global__ __launch_bounds__(256) void k4_fc(
    const u16* __restrict__ hcat, const float* __restrict__ fcw, const float* __restrict__ fcb,
    const float* __restrict__ lmp, const float* __restrict__ wfc, float* __restrict__ Pout)
{
  const int wv = threadIdx.x >> 6, lane = threadIdx.x & 63;
  const int lr = lane & 15, lq = lane >> 4;
  const int mt = blockIdx.x*4 + wv;
  short8 bfr[16];
  #pragma unroll
  for (int kk = 0; kk < 16; kk++){
    const float* wr = fcw + (size_t)lr*512 + kk*32 + lq*8;
    f32x4 w0 = *(const f32x4*)wr;
    f32x4 w1 = *(const f32x4*)(wr + 4);
    short8 sv;
    #pragma unroll
    for (int e = 0; e < 4; e++){ sv[e] = (short)f2bf(w0[e]); sv[4+e] = (short)f2bf(w1[e]); }
    bfr[kk] = sv;
  }
  f32x4 acc = (f32x4){0.f,0.f,0.f,0.f};
  #pragma unroll
  for (int kk = 0; kk < 16; kk++){
    short8 af = *(const short8*)(hcat + (size_t)(mt*16 + lr)*512 + kk*32 + lq*8);
    acc = __builtin_amdgcn_mfma_f32_16x16x32_bf16(af, bfr[kk], acc, 0,0,0);
  }
  const int cur = lr;
  float fb = fcb[cur];
  float wf = wfc[cur];
  #pragma unroll
  for (int r = 0; r < 4; r++){
    int m = mt*16 + lq*4 + r;
    int b = m & 63, s = m >> 6;
    float lmv = lmp[b*512 + s];
    Pout[(size_t)m*16 + cur] = acc[r] + fb + lmv*wf;
  }
}

// ---------------- K5: Viterbi — shuffle-free (replicated delta + readlane) ----------------
__global__ __launch_bounds__(64) void k5_vit(
    const float* __restrict__ Pg, const float* __restrict__ Am,
    float* __restrict__ dout, float* __restrict__ dl, u8* __restrict__ psi)
{
  const int b = blockIdx.x, lane = threadIdx.x;
  const int cur = lane & 15;
  float Ar[16];
  #pragma unroll
  for (int p = 0; p < 16; p++) Ar[p] = Am[p*16 + cur];
  float dreg[16];
  {
    float v0 = Pg[(size_t)b*16 + cur];
    if (lane < 16) dl[(size_t)b*16 + cur] = v0;
    #pragma unroll
    for (int c = 0; c < 16; c++) dreg[c] = rdlane_f(v0, c);
  }

#define FSTEP(X, S) { \
    float v_[16]; \
    _Pragma("unroll") \
    for (int p = 0; p < 16; p++) v_[p] = dreg[p] + Ar[p]; \
    float m1[8]; int i1[8]; \
    _Pragma("unroll") \
    for (int k = 0; k < 8; k++){ bool c_ = v_[2*k] >= v_[2*k+1]; \
      m1[k] = c_ ? v_[2*k] : v_[2*k+1]; i1[k] = c_ ? 2*k : 2*k+1; } \
    float m2[4]; int i2[4]; \
    _Pragma("unroll") \
    for (int k = 0; k < 4; k++){ bool c_ = m1[2*k] >= m1[2*k+1]; \
      m2[k] = c_ ? m1[2*k] : m1[2*k+1]; i2[k] = c_ ? i1[2*k] : i1[2*k+1]; } \
    float m3[2]; int i3[2]; \
    _Pragma("unroll") \
    for (int k = 0; k < 2; k++){ bool c_ = m2[2*k] >= m2[2*k+1]; \
      m3[k] = c_ ? m2[2*k] : m2[2*k+1]; i3[k] = c_ ? i2[2*k] : i2[2*k+1]; } \
    bool cf_ = m3[0] >= m3[1]; \
    float best = (cf_ ? m3[0] : m3[1]) + (X); \
    int bi = cf_ ? i3[0] : i3[1]; \
    if (lane < 16){ \
      dl[(size_t)((S)*64 + b)*16 + cur] = best; \
      psi[(size_t)((S)*64 + b)*16 + cur] = (u8)bi; \
    } \
    _Pragma("unroll") \
    for (int c = 0; c < 16; c++) dreg[c] = rdlane_f(best, c); \
  }

  float x0 = Pg[(size_t)(1*64 + b)*16 + cur];
  float x1 = Pg[(size_t)(2*64 + b)*16 + cur];
  float x2 = Pg[(size_t)(3*64 + b)*16 + cur];
  float x3 = Pg[(size_t)(4*64 + b)*16 + cur];
  for (int s = 1; s < 512; s += 4){
    FSTEP(x0, s);
    if (s + 4 < 512) x0 = Pg[(size_t)((s+4)*64 + b)*16 + cur];
    if (s + 1 < 512) FSTEP(x1, s+1);
    if (s + 5 < 512) x1 = Pg[(size_t)((s+5)*64 + b)*16 + cur];
    if (s + 2 < 512) FSTEP(x2, s+2);
    if (s + 6 < 512) x2 = Pg[(size_t)((s+6)*64 + b)*16 + cur];
    if (s + 3 < 512) FSTEP(x3, s+3);
    if (s + 7 < 512) x3 = Pg[(size_t)((s+7)*64 + b)*16 + cur];
  }
#undef FSTEP

  float bv = dreg[0]; int bix = 0;
  #pragma unroll
  for (int c = 1; c < 16; c++){ if (dreg[c] > bv){ bv = dreg[c]; bix = c; } }
  int tag = bix;
  float score = bv;
  if (lane == 0) dout[b*512 + 511] = (float)tag;

#define BSTEP(PV, DV, T) { \
    int prev = __builtin_amdgcn_readlane((PV), tag); \
    score += rdlane_f((DV), prev); \
    if (lane == 0) dout[b*512 + (T)] = (float)prev; \
    tag = prev; }

  int   p0 = 0, p1 = 0, p2 = 0, p3 = 0;
  float d0 = 0.f, d1 = 0.f, d2 = 0.f, d3 = 0.f;
  if (lane < 16){
    p0 = psi[(size_t)(511*64 + b)*16 + lane]; d0 = dl[(size_t)(510*64 + b)*16 + lane];
    p1 = psi[(size_t)(510*64 + b)*16 + lane]; d1 = dl[(size_t)(509*64 + b)*16 + lane];
    p2 = psi[(size_t)(509*64 + b)*16 + lane]; d2 = dl[(size_t)(508*64 + b)*16 + lane];
    p3 = psi[(size_t)(508*64 + b)*16 + lane]; d3 = dl[(size_t)(507*64 + b)*16 + lane];
  }
  for (int t = 510; t >= 0; t -= 4){
    BSTEP(p0, d0, t);
    if (t - 4 >= 0 && lane < 16){
      p0 = psi[(size_t)((t-3)*64 + b)*16 + lane]; d0 = dl[(size_t)((t-4)*64 + b)*16 + lane];
    }
    if (t - 1 >= 0) BSTEP(p1, d1, t-1);
    if (t - 5 >= 0 && lane < 16){
      p1 = psi[(size_t)((t-4)*64 + b)*16 + lane]; d1 = dl[(size_t)((t-5)*64 + b)*16 + lane];
    }
    if (t - 2 >= 0) BSTEP(p2, d2, t-2);
    if (t - 6 >= 0 && lane < 16){
      p2 = psi[(size_t)((t-5)*64 + b)*16 + lane]; d2 = dl[(size_t)((t-6)*64 + b)*16 + lane];
    }
    if (t - 3 >= 0) BSTEP(p3, d3, t-3);
    if (t - 7 >= 0 && lane < 16){
      p3 = psi[(size_t)((t-6)*64 + b)*16 + lane]; d3 = dl[(size_t)((t-7)*64 + b)*16 + lane];
    }
  }
#undef BSTEP
  if (lane == 0) dout[32768 + b] = score;
}

// ---------------- launcher ----------------
extern "C" void kernel_launch(void* const* d_in, const int* in_sizes, int n_in,
                              void* d_out, int out_size, void* d_ws, size_t ws_size,
                              hipStream_t stream)
{
  (void)in_sizes; (void)n_in; (void)out_size;
  if (ws_size < REQUIRED) return;

  const int*   X    = (const int*)d_in[0];
  const float* lm   = (const float*)d_in[1];
  const int*   tg   = (const int*)d_in[2];
  const int*   ch   = (const int*)d_in[3];
  const float* etab = (const float*)d_in[4];
  const float* ttab = (const float*)d_in[5];
  const float* ctab = (const float*)d_in[6];
  const float* cw   = (const float*)d_in[7];
  const float* cb   = (const float*)d_in[8];
  const float* wihf = (const float*)d_in[9];
  const float* whhf = (const float*)d_in[10];
  const float* bihf = (const float*)d_in[11];
  const float* bhhf = (const float*)d_in[12];
  const float* wihb = (const float*)d_in[13];
  const float* whhb = (const float*)d_in[14];
  const float* bihb = (const float*)d_in[15];
  const float* bhhb = (const float*)d_in[16];
  const float* fcw  = (const float*)d_in[17];
  const float* fcb  = (const float*)d_in[18];
  const float* Am   = (const float*)d_in[19];
  const float* wdp  = (const float*)d_in[20];

  char* ws = (char*)d_ws;
  u16*   gi   = (u16*)(ws + OFF_GI);
  u16*   feat = (u16*)(ws + OFF_B);
  u16*   hcat = (u16*)(ws + OFF_B);
  u16*   wih  = (u16*)(ws + OFF_WIH);
  s8*    wq   = (s8*)(ws + OFF_WQ);
  float* sc2  = (float*)(ws + OFF_SC);
  float* Pg   = (float*)(ws + OFF_P);
  float* dlt  = (float*)(ws + OFF_DL);
  u8*    psi  = (u8*)(ws + OFF_PSI);
  float* bias = (float*)(ws + OFF_BIAS);
  float* wfc  = (float*)(ws + OFF_WFC);
  float* dout = (float*)d_out;

  k01_fused<<<6657, 256, 0, stream>>>(X, tg, ch, etab, ttab, ctab, cw, cb, feat,
                                      whhf, whhb, wq, sc2,
                                      bihf, bhhf, bihb, bhhb, fcw, wdp, bias, wfc,
                                      wihf, wihb, wih);
  k2_gemm<<<dim3(16, 256), 256, 0, stream>>>(feat, wih, bias, gi);
  k3_lstm<<<64, 512, 0, stream>>>(wq, sc2, gi, hcat);
  k4_fc<<<512, 256, 0, stream>>>(hcat, fcw, fcb, lm, wfc, Pg);
  k5_vit<<<64, 64, 0, stream>>>(Pg, Am, dout, dlt, psi);
}